// Round 1
// baseline (15.247 us; speedup 1.0000x reference)
//
#include <hip/hip_runtime.h>
#include <math.h>

#define HID 64

__global__ __launch_bounds__(1024) void spatial_attn_fused(
    const float* __restrict__ x,   // [B, N] flat
    const float* __restrict__ Wq, const float* __restrict__ bq,
    const float* __restrict__ Wk, const float* __restrict__ bk,
    const float* __restrict__ Wv, const float* __restrict__ bv,
    const float* __restrict__ Wo, const float* __restrict__ bo,
    float* __restrict__ out,       // [B, N] flat
    int N)
{
    const int b = blockIdx.x;
    const int tid = threadIdx.x;
    const int nthreads = blockDim.x;
    const float* xb = x + (size_t)b * N;
    float* yb = out + (size_t)b * N;

    // ---------------- Pass 1: S1 = sum x, S2 = sum x^2 ----------------
    float s1 = 0.f, s2 = 0.f;
    const int nvec = N >> 2;  // N = 7396 -> 1849 float4s
    const float4* xv = reinterpret_cast<const float4*>(xb);
    for (int i = tid; i < nvec; i += nthreads) {
        float4 v = xv[i];
        s1 += v.x + v.y + v.z + v.w;
        s2 += v.x * v.x + v.y * v.y + v.z * v.z + v.w * v.w;
    }
    for (int i = (nvec << 2) + tid; i < N; i += nthreads) {  // tail (none for 7396)
        float v = xb[i];
        s1 += v; s2 += v * v;
    }
    // wave (64-lane) reduce
    for (int off = 32; off > 0; off >>= 1) {
        s1 += __shfl_down(s1, off);
        s2 += __shfl_down(s2, off);
    }
    __shared__ float lds1[16], lds2[16];
    __shared__ float sS1, sS2, sAlpha, sBeta;
    const int wave = tid >> 6, lane = tid & 63;
    const int nwaves = nthreads >> 6;
    if (lane == 0) { lds1[wave] = s1; lds2[wave] = s2; }
    __syncthreads();
    if (tid == 0) {
        float a = 0.f, c = 0.f;
        for (int w = 0; w < nwaves; ++w) { a += lds1[w]; c += lds2[w]; }
        sS1 = a; sS2 = c;
    }
    __syncthreads();
    const float S1 = sS1, S2 = sS2;

    // ---------------- Per-row softmax on wave 0 (one lane per head h) ----
    if (tid < HID) {
        const int h = tid;
        const float wqh = Wq[h], bqh = bq[h];
        const float scale = 0.125f;  // 1/sqrt(64)
        const float fN = (float)N;

        float m = -INFINITY;
        for (int g = 0; g < HID; ++g) {
            float wkg = Wk[g], bkg = bk[g];
            float sc = (wqh * wkg * S2 + (wqh * bkg + bqh * wkg) * S1 + bqh * bkg * fN) * scale;
            m = fmaxf(m, sc);
        }
        float sum = 0.f, sumA = 0.f, sumB = 0.f;
        for (int g = 0; g < HID; ++g) {
            float wkg = Wk[g], bkg = bk[g];
            float sc = (wqh * wkg * S2 + (wqh * bkg + bqh * wkg) * S1 + bqh * bkg * fN) * scale;
            float e = __expf(sc - m);
            sum += e;
            sumA += e * Wv[g];
            sumB += e * bv[g];
        }
        const float inv = 1.f / sum;
        const float woh = Wo[h];
        float ca = woh * (sumA * inv);
        float cb = woh * (sumB * inv);
        for (int off = 32; off > 0; off >>= 1) {
            ca += __shfl_down(ca, off);
            cb += __shfl_down(cb, off);
        }
        if (h == 0) { sAlpha = ca; sBeta = cb + bo[0]; }
    }
    __syncthreads();
    const float alpha = sAlpha, beta = sBeta;

    // ---------------- Pass 2: y = alpha * x + beta ----------------
    float4* yv = reinterpret_cast<float4*>(yb);
    for (int i = tid; i < nvec; i += nthreads) {
        float4 v = xv[i];
        float4 r;
        r.x = fmaf(alpha, v.x, beta);
        r.y = fmaf(alpha, v.y, beta);
        r.z = fmaf(alpha, v.z, beta);
        r.w = fmaf(alpha, v.w, beta);
        yv[i] = r;
    }
    for (int i = (nvec << 2) + tid; i < N; i += nthreads) {
        yb[i] = fmaf(alpha, xb[i], beta);
    }
}

extern "C" void kernel_launch(void* const* d_in, const int* in_sizes, int n_in,
                              void* d_out, int out_size, void* d_ws, size_t ws_size,
                              hipStream_t stream) {
    const float* x  = (const float*)d_in[0];
    const float* Wq = (const float*)d_in[1];
    const float* bq = (const float*)d_in[2];
    const float* Wk = (const float*)d_in[3];
    const float* bk = (const float*)d_in[4];
    const float* Wv = (const float*)d_in[5];
    const float* bv = (const float*)d_in[6];
    const float* Wo = (const float*)d_in[7];
    const float* bo = (const float*)d_in[8];
    float* out = (float*)d_out;

    const int B = 64;
    const int N = in_sizes[0] / B;  // 86*86 = 7396

    spatial_attn_fused<<<B, 1024, 0, stream>>>(x, Wq, bq, Wk, bk, Wv, bv, Wo, bo, out, N);
}

// Round 2
// 12.473 us; speedup vs baseline: 1.2224x; 1.2224x over previous
//
#include <hip/hip_runtime.h>
#include <math.h>

#define HID 64
#define CHUNKS 4
#define NTHREADS 1024

__global__ __launch_bounds__(NTHREADS) void spatial_attn_fused(
    const float* __restrict__ x,   // [B, N] flat
    const float* __restrict__ Wq, const float* __restrict__ bq,
    const float* __restrict__ Wk, const float* __restrict__ bk,
    const float* __restrict__ Wv, const float* __restrict__ bv,
    const float* __restrict__ Wo, const float* __restrict__ bo,
    float* __restrict__ out,       // [B, N] flat
    int N)
{
    // bid = b + 64*chunk  ->  the 4 blocks of one batch land on the same XCD
    // (64 % 8 == 0), so their redundant pass-1 reads share one L2.
    const int bid   = blockIdx.x;
    const int b     = bid & 63;
    const int chunk = bid >> 6;
    const int tid   = threadIdx.x;
    const float* xb = x   + (size_t)b * N;
    float*       yb = out + (size_t)b * N;

    // ---------------- Pass 1 (redundant per chunk): S1 = Σx, S2 = Σx² ------
    float s1 = 0.f, s2 = 0.f;
    const int nvec = N >> 2;                       // 7396 -> 1849 float4s
    const float4* xv = reinterpret_cast<const float4*>(xb);
    for (int i = tid; i < nvec; i += NTHREADS) {
        float4 v = xv[i];
        s1 += (v.x + v.y) + (v.z + v.w);
        s2 += v.x * v.x + v.y * v.y + v.z * v.z + v.w * v.w;
    }
    for (int i = (nvec << 2) + tid; i < N; i += NTHREADS) {  // tail (none for 7396)
        float v = xb[i];
        s1 += v; s2 += v * v;
    }
    #pragma unroll
    for (int off = 32; off > 0; off >>= 1) {
        s1 += __shfl_down(s1, off);
        s2 += __shfl_down(s2, off);
    }
    __shared__ float lds1[16], lds2[16], ldsA[16], ldsB[16];
    __shared__ float sS1, sS2, sAlpha, sBeta;
    const int wave = tid >> 6, lane = tid & 63;
    if (lane == 0) { lds1[wave] = s1; lds2[wave] = s2; }
    __syncthreads();
    if (tid == 0) {
        float a = 0.f, c = 0.f;
        #pragma unroll
        for (int w = 0; w < NTHREADS / 64; ++w) { a += lds1[w]; c += lds2[w]; }
        sS1 = a; sS2 = c;
    }
    __syncthreads();
    const float S1 = sS1, S2 = sS2;

    // ---------------- Softmax, wave-parallel: wave w owns heads 4w..4w+3 ---
    // sc[h][g] = P_h * wk_g + Q_h * bk_g   (rank-2 score matrix, C==1)
    const float scale = 0.125f;           // 1/sqrt(64)
    const float fN = (float)N;
    const float wk_g = Wk[lane], bk_g = bk[lane];
    const float wv_g = Wv[lane], bv_g = bv[lane];
    float cA = 0.f, cB = 0.f;
    #pragma unroll
    for (int j = 0; j < HID / (NTHREADS / 64); ++j) {   // 4 heads per wave
        const int h = wave * (HID / (NTHREADS / 64)) + j;
        const float wqh = Wq[h], bqh = bq[h];           // wave-uniform loads
        const float P = (wqh * S2 + bqh * S1) * scale;
        const float Q = (wqh * S1 + bqh * fN) * scale;
        const float sc = P * wk_g + Q * bk_g;
        float m = sc;
        #pragma unroll
        for (int off = 32; off > 0; off >>= 1) m = fmaxf(m, __shfl_xor(m, off));
        const float e = __expf(sc - m);
        float s = e, sA = e * wv_g, sB = e * bv_g;
        #pragma unroll
        for (int off = 32; off > 0; off >>= 1) {
            s  += __shfl_xor(s,  off);
            sA += __shfl_xor(sA, off);
            sB += __shfl_xor(sB, off);
        }
        const float inv = 1.f / s;
        const float woh = Wo[h];
        cA += woh * (sA * inv);
        cB += woh * (sB * inv);
    }
    if (lane == 0) { ldsA[wave] = cA; ldsB[wave] = cB; }
    __syncthreads();
    if (tid == 0) {
        float a = 0.f, c = 0.f;
        #pragma unroll
        for (int w = 0; w < NTHREADS / 64; ++w) { a += ldsA[w]; c += ldsB[w]; }
        sAlpha = a; sBeta = c + bo[0];
    }
    __syncthreads();
    const float alpha = sAlpha, beta = sBeta;

    // ---------------- Pass 2: this block writes its contiguous quarter -----
    const int i0 = (chunk * nvec) / CHUNKS;
    const int i1 = ((chunk + 1) * nvec) / CHUNKS;
    float4* yv = reinterpret_cast<float4*>(yb);
    for (int i = i0 + tid; i < i1; i += NTHREADS) {
        float4 v = xv[i];                 // L1-hot: this block read it in pass 1
        float4 r;
        r.x = fmaf(alpha, v.x, beta);
        r.y = fmaf(alpha, v.y, beta);
        r.z = fmaf(alpha, v.z, beta);
        r.w = fmaf(alpha, v.w, beta);
        yv[i] = r;
    }
    if (chunk == CHUNKS - 1) {
        for (int i = (nvec << 2) + tid; i < N; i += NTHREADS)
            yb[i] = fmaf(alpha, xb[i], beta);
    }
}

extern "C" void kernel_launch(void* const* d_in, const int* in_sizes, int n_in,
                              void* d_out, int out_size, void* d_ws, size_t ws_size,
                              hipStream_t stream) {
    const float* x  = (const float*)d_in[0];
    const float* Wq = (const float*)d_in[1];
    const float* bq = (const float*)d_in[2];
    const float* Wk = (const float*)d_in[3];
    const float* bk = (const float*)d_in[4];
    const float* Wv = (const float*)d_in[5];
    const float* bv = (const float*)d_in[6];
    const float* Wo = (const float*)d_in[7];
    const float* bo = (const float*)d_in[8];
    float* out = (float*)d_out;

    const int B = 64;
    const int N = in_sizes[0] / B;  // 86*86 = 7396

    spatial_attn_fused<<<B * CHUNKS, NTHREADS, 0, stream>>>(
        x, Wq, bq, Wk, bk, Wv, bv, Wo, bo, out, N);
}